// Round 1
// baseline (677.949 us; speedup 1.0000x reference)
//
#include <hip/hip_runtime.h>
#include <math.h>

#define Bc 2
#define Nc 2048
#define Dc 512
#define Hc 8
#define DKc 64
#define NEGV -1e9f
#define TS 64

// XOR swizzle for 64-wide LDS tiles: element (row, col) -> row*64 + (col ^ ((row&15)<<2)).
// Keeps float4 groups contiguous (xor touches bits >=2) and makes both the
// transposed writes and the broadcast/strided reads conflict-light.
__device__ __forceinline__ int sw(int row, int col) {
    return (row << 6) + (col ^ ((row & 15) << 2));
}

// Pack a [2][N][N] int32 0/1 mask into bitmask words [2][N][N/32].
__global__ __launch_bounds__(256) void pack_mask(const int* __restrict__ src,
                                                 unsigned* __restrict__ dst) {
    int w = blockIdx.x * 256 + threadIdx.x;              // word id, 2*N*64 total
    const int4* p = (const int4*)(src + ((size_t)(w >> 6) * Nc) + ((w & 63) << 5));
    unsigned bits = 0u;
#pragma unroll
    for (int u = 0; u < 8; ++u) {
        int4 v = p[u];
        bits |= (v.x ? 1u : 0u) << (4 * u + 0);
        bits |= (v.y ? 1u : 0u) << (4 * u + 1);
        bits |= (v.z ? 1u : 0u) << (4 * u + 2);
        bits |= (v.w ? 1u : 0u) << (4 * u + 3);
    }
    dst[w] = bits;
}

// C[m][j] = scale * sum_k A[m][k] * W[j][k]   (y = x @ W^T, nn.Linear semantics)
// head_layout=1: scatter C into [B,H,N,dk] (j = h*64+t, m = b*2048+n).
__global__ __launch_bounds__(256) void gemm_xwt(
    const float* __restrict__ A, const float* __restrict__ W, float* __restrict__ C,
    int M, int K, int Nout, float scale, int head_layout)
{
    __shared__ float At[TS * TS];  // [k][m] transposed, swizzled
    __shared__ float Wt[TS * TS];  // [k][n] transposed, swizzled
    int t = threadIdx.x;
    int tx = t & 15, ty = t >> 4;
    int m0 = blockIdx.x * TS, n0 = blockIdx.y * TS;
    float acc[4][4] = {};
    for (int k0 = 0; k0 < K; k0 += TS) {
        __syncthreads();
#pragma unroll
        for (int p = 0; p < 4; ++p) {
            int idx = p * 256 + t;
            int r  = idx >> 4;
            int c4 = (idx & 15) << 2;
            float4 av = *(const float4*)&A[(size_t)(m0 + r) * K + k0 + c4];
            At[sw(c4 + 0, r)] = av.x;
            At[sw(c4 + 1, r)] = av.y;
            At[sw(c4 + 2, r)] = av.z;
            At[sw(c4 + 3, r)] = av.w;
            float4 wv = *(const float4*)&W[(size_t)(n0 + r) * K + k0 + c4];
            Wt[sw(c4 + 0, r)] = wv.x;
            Wt[sw(c4 + 1, r)] = wv.y;
            Wt[sw(c4 + 2, r)] = wv.z;
            Wt[sw(c4 + 3, r)] = wv.w;
        }
        __syncthreads();
#pragma unroll 8
        for (int kk = 0; kk < TS; ++kk) {
            float4 a = *(const float4*)&At[sw(kk, ty << 2)];
            float4 w = *(const float4*)&Wt[sw(kk, tx << 2)];
            acc[0][0] += a.x * w.x; acc[0][1] += a.x * w.y; acc[0][2] += a.x * w.z; acc[0][3] += a.x * w.w;
            acc[1][0] += a.y * w.x; acc[1][1] += a.y * w.y; acc[1][2] += a.y * w.z; acc[1][3] += a.y * w.w;
            acc[2][0] += a.z * w.x; acc[2][1] += a.z * w.y; acc[2][2] += a.z * w.z; acc[2][3] += a.z * w.w;
            acc[3][0] += a.w * w.x; acc[3][1] += a.w * w.y; acc[3][2] += a.w * w.z; acc[3][3] += a.w * w.w;
        }
    }
#pragma unroll
    for (int ri = 0; ri < 4; ++ri) {
        int m = m0 + (ty << 2) + ri;
        int j = n0 + (tx << 2);
        float4 o = make_float4(acc[ri][0] * scale, acc[ri][1] * scale,
                               acc[ri][2] * scale, acc[ri][3] * scale);
        size_t dst;
        if (head_layout) {
            int b = m >> 11, n = m & (Nc - 1);
            int h = j >> 6, tt = j & 63;
            dst = ((size_t)(b * Hc + h) * Nc + n) * DKc + tt;
        } else {
            dst = (size_t)m * Nout + j;
        }
        *(float4*)&C[dst] = o;
    }
}

// Flash-style attention per (b,h): Br=Bc=64 tiles, online softmax with the
// reference's exact -1e9 mask substitution (NOT -inf), O -> [B,N,D].
__global__ __launch_bounds__(256) void attn_kernel(
    const float* __restrict__ Q,   // [B,H,N,DK], pre-scaled by 1/sqrt(dk)
    const float* __restrict__ Kb,  // [B,H,N,DK]
    const float* __restrict__ Vb,  // [B,H,N,DK]
    const unsigned* __restrict__ pseq,  // [B][N][N/32]
    const unsigned* __restrict__ psp,   // [2][N][N/32]
    float* __restrict__ Ob)             // [B,N,D]
{
    __shared__ float Qt[TS * TS];  // [dk][r]
    __shared__ float Kt[TS * TS];  // [dk][c]
    __shared__ float Vs[TS * TS];  // [j][d]
    __shared__ float Pt[TS * TS];  // [j][r]

    int t = threadIdx.x;
    int tx = t & 15, ty = t >> 4;
    int r0 = ty << 2, c0 = tx << 2;
    int bh = blockIdx.y;
    int b = bh >> 3, h = bh & 7, par = h & 1;
    int i0 = blockIdx.x * TS;

    const float* Qp = Q  + ((size_t)bh * Nc + i0) * DKc;
    const float* Kp = Kb + (size_t)bh * Nc * DKc;
    const float* Vp = Vb + (size_t)bh * Nc * DKc;

    // stage Q tile transposed (once per block)
#pragma unroll
    for (int p = 0; p < 4; ++p) {
        int idx = p * 256 + t;
        int r  = idx >> 4;
        int c4 = (idx & 15) << 2;
        float4 v = *(const float4*)&Qp[r * DKc + c4];
        Qt[sw(c4 + 0, r)] = v.x;
        Qt[sw(c4 + 1, r)] = v.y;
        Qt[sw(c4 + 2, r)] = v.z;
        Qt[sw(c4 + 3, r)] = v.w;
    }

    float m_r[4], l_r[4], o_acc[4][4] = {};
#pragma unroll
    for (int i = 0; i < 4; ++i) { m_r[i] = -INFINITY; l_r[i] = 0.f; }

    int wq = c0 >> 5;        // word within row for this thread's 4 cols (tile-local)
    int bitbase = c0 & 31;

    for (int j0 = 0; j0 < Nc; j0 += TS) {
        __syncthreads();     // prev PV reads done before restaging K/V
#pragma unroll
        for (int p = 0; p < 4; ++p) {
            int idx = p * 256 + t;
            int r  = idx >> 4;
            int c4 = (idx & 15) << 2;
            float4 kv = *(const float4*)&Kp[(size_t)(j0 + r) * DKc + c4];
            Kt[sw(c4 + 0, r)] = kv.x;
            Kt[sw(c4 + 1, r)] = kv.y;
            Kt[sw(c4 + 2, r)] = kv.z;
            Kt[sw(c4 + 3, r)] = kv.w;
            float4 vv = *(const float4*)&Vp[(size_t)(j0 + r) * DKc + c4];
            *(float4*)&Vs[sw(r, c4)] = vv;
        }
        __syncthreads();

        // S = (Q/sqrt(dk)) @ K^T, 4x4 per thread
        float s[4][4] = {};
#pragma unroll 8
        for (int kk = 0; kk < TS; ++kk) {
            float4 a = *(const float4*)&Qt[sw(kk, r0)];
            float4 k = *(const float4*)&Kt[sw(kk, c0)];
            s[0][0] += a.x * k.x; s[0][1] += a.x * k.y; s[0][2] += a.x * k.z; s[0][3] += a.x * k.w;
            s[1][0] += a.y * k.x; s[1][1] += a.y * k.y; s[1][2] += a.y * k.z; s[1][3] += a.y * k.w;
            s[2][0] += a.z * k.x; s[2][1] += a.z * k.y; s[2][2] += a.z * k.z; s[2][3] += a.z * k.w;
            s[3][0] += a.w * k.x; s[3][1] += a.w * k.y; s[3][2] += a.w * k.z; s[3][3] += a.w * k.w;
        }

        // masks + online softmax (row groups = 16 consecutive lanes, shfl_xor reduce)
        float pv[4][4];
        int wrd = ((j0 + c0) >> 5);
#pragma unroll
        for (int ri = 0; ri < 4; ++ri) {
            int i = i0 + r0 + ri;
            unsigned mw = pseq[(((size_t)b * Nc + i) << 6) + wrd] &
                          psp [(((size_t)par * Nc + i) << 6) + wrd];
#pragma unroll
            for (int ci = 0; ci < 4; ++ci)
                if (!((mw >> (bitbase + ci)) & 1u)) s[ri][ci] = NEGV;
            float mx = fmaxf(fmaxf(s[ri][0], s[ri][1]), fmaxf(s[ri][2], s[ri][3]));
            mx = fmaxf(mx, __shfl_xor(mx, 1));
            mx = fmaxf(mx, __shfl_xor(mx, 2));
            mx = fmaxf(mx, __shfl_xor(mx, 4));
            mx = fmaxf(mx, __shfl_xor(mx, 8));
            float mnew = fmaxf(m_r[ri], mx);
            float alpha = __expf(m_r[ri] - mnew);   // first tile: exp(-inf)=0
            m_r[ri] = mnew;
            float ssum = 0.f;
#pragma unroll
            for (int ci = 0; ci < 4; ++ci) {
                float e = __expf(s[ri][ci] - mnew);
                pv[ri][ci] = e;
                ssum += e;
            }
            ssum += __shfl_xor(ssum, 1);
            ssum += __shfl_xor(ssum, 2);
            ssum += __shfl_xor(ssum, 4);
            ssum += __shfl_xor(ssum, 8);
            l_r[ri] = l_r[ri] * alpha + ssum;
#pragma unroll
            for (int ci = 0; ci < 4; ++ci) o_acc[ri][ci] *= alpha;
        }
        // P -> LDS ([j][r] layout for PV phase)
#pragma unroll
        for (int ci = 0; ci < 4; ++ci) {
            *(float4*)&Pt[sw(c0 + ci, r0)] =
                make_float4(pv[0][ci], pv[1][ci], pv[2][ci], pv[3][ci]);
        }
        __syncthreads();

        // O += P @ V, thread owns rows r0..+3, dims c0..+3
#pragma unroll 8
        for (int j = 0; j < TS; ++j) {
            float4 p4 = *(const float4*)&Pt[sw(j, r0)];
            float4 v4 = *(const float4*)&Vs[sw(j, c0)];
            o_acc[0][0] += p4.x * v4.x; o_acc[0][1] += p4.x * v4.y; o_acc[0][2] += p4.x * v4.z; o_acc[0][3] += p4.x * v4.w;
            o_acc[1][0] += p4.y * v4.x; o_acc[1][1] += p4.y * v4.y; o_acc[1][2] += p4.y * v4.z; o_acc[1][3] += p4.y * v4.w;
            o_acc[2][0] += p4.z * v4.x; o_acc[2][1] += p4.z * v4.y; o_acc[2][2] += p4.z * v4.z; o_acc[2][3] += p4.z * v4.w;
            o_acc[3][0] += p4.w * v4.x; o_acc[3][1] += p4.w * v4.y; o_acc[3][2] += p4.w * v4.z; o_acc[3][3] += p4.w * v4.w;
        }
    }

#pragma unroll
    for (int ri = 0; ri < 4; ++ri) {
        float inv = 1.0f / l_r[ri];
        int i = i0 + r0 + ri;
        float4 o = make_float4(o_acc[ri][0] * inv, o_acc[ri][1] * inv,
                               o_acc[ri][2] * inv, o_acc[ri][3] * inv);
        *(float4*)&Ob[((size_t)b * Nc + i) * Dc + h * DKc + c0] = o;
    }
    (void)wq;
}

extern "C" void kernel_launch(void* const* d_in, const int* in_sizes, int n_in,
                              void* d_out, int out_size, void* d_ws, size_t ws_size,
                              hipStream_t stream) {
    const float* x  = (const float*)d_in[0];
    const float* Wq = (const float*)d_in[1];
    const float* Wk = (const float*)d_in[2];
    const float* Wv = (const float*)d_in[3];
    const float* Wo = (const float*)d_in[4];
    const int* seqm = (const int*)d_in[5];
    const int* spm  = (const int*)d_in[6];
    float* out = (float*)d_out;

    const size_t QSZ = (size_t)Bc * Hc * Nc * DKc;   // 2,097,152 floats each
    float* Qb = (float*)d_ws;
    float* Kb = Qb + QSZ;
    float* Vb = Kb + QSZ;
    float* Oi = Vb + QSZ;                            // attention output [B,N,D]
    unsigned* pseq = (unsigned*)(Oi + QSZ);          // [2][N][64] words
    unsigned* psp  = pseq + (size_t)Bc * Nc * (Nc / 32);

    // 1) bit-pack masks (reads the 67 MB of int32 masks exactly once)
    hipLaunchKernelGGL(pack_mask, dim3(2 * Nc * 64 / 256), dim3(256), 0, stream, seqm, pseq);
    hipLaunchKernelGGL(pack_mask, dim3(2 * Nc * 64 / 256), dim3(256), 0, stream, spm, psp);

    // 2) Q/K/V projections (scale 1/sqrt(64)=0.125 folded into Q)
    dim3 gg(Bc * Nc / TS, Dc / TS);                  // (64, 8)
    hipLaunchKernelGGL(gemm_xwt, gg, dim3(256), 0, stream, x, Wq, Qb, Bc * Nc, Dc, Dc, 0.125f, 1);
    hipLaunchKernelGGL(gemm_xwt, gg, dim3(256), 0, stream, x, Wk, Kb, Bc * Nc, Dc, Dc, 1.0f, 1);
    hipLaunchKernelGGL(gemm_xwt, gg, dim3(256), 0, stream, x, Wv, Vb, Bc * Nc, Dc, Dc, 1.0f, 1);

    // 3) fused masked flash attention
    hipLaunchKernelGGL(attn_kernel, dim3(Nc / TS, Bc * Hc), dim3(256), 0, stream,
                       Qb, Kb, Vb, pseq, psp, Oi);

    // 4) output projection
    hipLaunchKernelGGL(gemm_xwt, gg, dim3(256), 0, stream, Oi, Wo, out, Bc * Nc, Dc, Dc, 1.0f, 0);
}

// Round 2
// 322.002 us; speedup vs baseline: 2.1054x; 2.1054x over previous
//
#include <hip/hip_runtime.h>
#include <math.h>

#define Bc 2
#define Nc 2048
#define Dc 512
#define Hc 8
#define NEGV -1e9f

typedef __bf16 bf16;
typedef __bf16 bf16x8 __attribute__((ext_vector_type(8)));
typedef float f32x4 __attribute__((ext_vector_type(4)));

#define MFMA(a, b, c) __builtin_amdgcn_mfma_f32_16x16x32_bf16(a, b, c, 0, 0, 0)

// 16-lane-group reductions on the VALU via DPP (keeps the LDS pipe free).
template <int CTRL>
__device__ __forceinline__ float dppf(float v) {
    int i = __builtin_bit_cast(int, v);
    i = __builtin_amdgcn_mov_dpp(i, CTRL, 0xf, 0xf, true);
    return __builtin_bit_cast(float, i);
}
__device__ __forceinline__ float red_max16(float v) {
    v = fmaxf(v, dppf<0xB1>(v));   // quad_perm [1,0,3,2]
    v = fmaxf(v, dppf<0x4E>(v));   // quad_perm [2,3,0,1]
    v = fmaxf(v, dppf<0x141>(v));  // row_half_mirror
    v = fmaxf(v, dppf<0x140>(v));  // row_mirror
    return v;
}
__device__ __forceinline__ float red_sum16(float v) {
    v += dppf<0xB1>(v);
    v += dppf<0x4E>(v);
    v += dppf<0x141>(v);
    v += dppf<0x140>(v);
    return v;
}

// Pack [2][N][N] int32 0/1 mask into bit words [2][N][N/32].
__global__ __launch_bounds__(256) void pack_mask(const int* __restrict__ src,
                                                 unsigned* __restrict__ dst) {
    int w = blockIdx.x * 256 + threadIdx.x;
    const int4* p = (const int4*)(src + ((size_t)(w >> 6) * Nc) + ((w & 63) << 5));
    unsigned bits = 0u;
#pragma unroll
    for (int u = 0; u < 8; ++u) {
        int4 v = p[u];
        bits |= (v.x ? 1u : 0u) << (4 * u + 0);
        bits |= (v.y ? 1u : 0u) << (4 * u + 1);
        bits |= (v.z ? 1u : 0u) << (4 * u + 2);
        bits |= (v.w ? 1u : 0u) << (4 * u + 3);
    }
    dst[w] = bits;
}

// fp32 -> bf16 (8 elements / thread)
__global__ __launch_bounds__(256) void cvt_bf16(const float* __restrict__ src, bf16* __restrict__ dst) {
    int i = (blockIdx.x * 256 + threadIdx.x) * 8;
    float4 a = *(const float4*)&src[i];
    float4 c = *(const float4*)&src[i + 4];
    float v[8] = {a.x, a.y, a.z, a.w, c.x, c.y, c.z, c.w};
    bf16x8 o;
#pragma unroll
    for (int u = 0; u < 8; ++u) o[u] = (bf16)v[u];
    *(bf16x8*)&dst[i] = o;
}

// Wq/Wk/Wv -> single bf16 (Wb[z]); Wo -> hi/lo split pair.
__global__ __launch_bounds__(256) void cvt_weights(const float* __restrict__ Wq, const float* __restrict__ Wk,
                                                   const float* __restrict__ Wv, const float* __restrict__ Wo,
                                                   bf16* __restrict__ Wb, bf16* __restrict__ Woh,
                                                   bf16* __restrict__ Wol) {
    int i = (blockIdx.x * 256 + threadIdx.x) * 8;
    int z = blockIdx.y;
    const float* src = (z == 0) ? Wq : (z == 1) ? Wk : (z == 2) ? Wv : Wo;
    float4 a = *(const float4*)&src[i];
    float4 c = *(const float4*)&src[i + 4];
    float v[8] = {a.x, a.y, a.z, a.w, c.x, c.y, c.z, c.w};
    if (z < 3) {
        bf16x8 o;
#pragma unroll
        for (int u = 0; u < 8; ++u) o[u] = (bf16)v[u];
        *(bf16x8*)&Wb[(size_t)z * 262144 + i] = o;
    } else {
        bf16x8 oh, ol;
#pragma unroll
        for (int u = 0; u < 8; ++u) {
            bf16 hi = (bf16)v[u];
            oh[u] = hi;
            ol[u] = (bf16)(v[u] - (float)hi);
        }
        *(bf16x8*)&Woh[i] = oh;
        *(bf16x8*)&Wol[i] = ol;
    }
}

// C = scale*(A @ W^T), bf16 MFMA, no LDS (frags direct from global; W is L2-hot).
// Output scattered bf16 into head layout [B,H,N,64].
__global__ __launch_bounds__(256) void gemm_qkv(const bf16* __restrict__ A, const bf16* __restrict__ W,
                                                bf16* __restrict__ out, float scale) {
    int t = threadIdx.x, wave = t >> 6, lane = t & 63, l = lane & 15, quad = lane >> 4;
    int m0 = blockIdx.x * 64 + wave * 16;
    int n0 = blockIdx.y * 64;
    f32x4 acc[4] = {};
    const bf16* Ap = A + (size_t)(m0 + l) * 512;
    for (int k0 = 0; k0 < 512; k0 += 64) {
        bf16x8 a0 = *(const bf16x8*)&Ap[k0 + quad * 8];
        bf16x8 a1 = *(const bf16x8*)&Ap[k0 + 32 + quad * 8];
#pragma unroll
        for (int nc = 0; nc < 4; ++nc) {
            const bf16* Wp = W + (size_t)(n0 + nc * 16 + l) * 512 + k0 + quad * 8;
            bf16x8 b0 = *(const bf16x8*)&Wp[0];
            bf16x8 b1 = *(const bf16x8*)&Wp[32];
            acc[nc] = MFMA(a0, b0, acc[nc]);
            acc[nc] = MFMA(a1, b1, acc[nc]);
        }
    }
#pragma unroll
    for (int nc = 0; nc < 4; ++nc) {
#pragma unroll
        for (int r = 0; r < 4; ++r) {
            int m = m0 + quad * 4 + r;
            int feat = n0 + nc * 16 + l;
            int b = m >> 11, tok = m & 2047, h = feat >> 6, d = feat & 63;
            out[(((size_t)(b * 8 + h)) * 2048 + tok) * 64 + d] = (bf16)(acc[nc][r] * scale);
        }
    }
}

// Final projection: C = Oh*Woh^T + Oh*Wol^T + Ol*Woh^T (split-bf16, ~fp32 accurate), fp32 out.
__global__ __launch_bounds__(256) void gemm_out(const bf16* __restrict__ Ah, const bf16* __restrict__ Al,
                                                const bf16* __restrict__ Wh, const bf16* __restrict__ Wl,
                                                float* __restrict__ C) {
    int t = threadIdx.x, wave = t >> 6, lane = t & 63, l = lane & 15, quad = lane >> 4;
    int m0 = blockIdx.x * 64 + wave * 16;
    int n0 = blockIdx.y * 64;
    f32x4 acc[4] = {};
    const bf16* Ahp = Ah + (size_t)(m0 + l) * 512;
    const bf16* Alp = Al + (size_t)(m0 + l) * 512;
    for (int k0 = 0; k0 < 512; k0 += 64) {
        bf16x8 ah0 = *(const bf16x8*)&Ahp[k0 + quad * 8];
        bf16x8 ah1 = *(const bf16x8*)&Ahp[k0 + 32 + quad * 8];
        bf16x8 al0 = *(const bf16x8*)&Alp[k0 + quad * 8];
        bf16x8 al1 = *(const bf16x8*)&Alp[k0 + 32 + quad * 8];
#pragma unroll
        for (int nc = 0; nc < 4; ++nc) {
            const bf16* Whp = Wh + (size_t)(n0 + nc * 16 + l) * 512 + k0 + quad * 8;
            const bf16* Wlp = Wl + (size_t)(n0 + nc * 16 + l) * 512 + k0 + quad * 8;
            bf16x8 bh0 = *(const bf16x8*)&Whp[0];
            bf16x8 bh1 = *(const bf16x8*)&Whp[32];
            bf16x8 bl0 = *(const bf16x8*)&Wlp[0];
            bf16x8 bl1 = *(const bf16x8*)&Wlp[32];
            acc[nc] = MFMA(ah0, bh0, acc[nc]);
            acc[nc] = MFMA(ah1, bh1, acc[nc]);
            acc[nc] = MFMA(ah0, bl0, acc[nc]);
            acc[nc] = MFMA(ah1, bl1, acc[nc]);
            acc[nc] = MFMA(al0, bh0, acc[nc]);
            acc[nc] = MFMA(al1, bh1, acc[nc]);
        }
    }
#pragma unroll
    for (int nc = 0; nc < 4; ++nc) {
#pragma unroll
        for (int r = 0; r < 4; ++r)
            C[(size_t)(m0 + quad * 4 + r) * 512 + n0 + nc * 16 + l] = acc[nc][r];
    }
}

// V [bh][2048][64] -> Vt [bh][64][2048] bf16 (so attention's PV B-frags are contiguous 16B).
__global__ __launch_bounds__(256) void transpose_v(const bf16* __restrict__ V, bf16* __restrict__ Vt) {
    __shared__ bf16 T[64 * 72];
    int t = threadIdx.x;
    int j0 = blockIdx.x * 64;
    int bh = blockIdx.y;
#pragma unroll
    for (int it = 0; it < 2; ++it) {
        int u = it * 256 + t;
        int r = u >> 3, c = u & 7;
        *(bf16x8*)&T[r * 72 + c * 8] = *(const bf16x8*)&V[((size_t)bh * 2048 + j0 + r) * 64 + c * 8];
    }
    __syncthreads();
#pragma unroll
    for (int it = 0; it < 2; ++it) {
        int u = it * 256 + t;
        int d = u >> 3, c = u & 7;
        bf16x8 o;
#pragma unroll
        for (int i = 0; i < 8; ++i) o[i] = T[(c * 8 + i) * 72 + d];
        *(bf16x8*)&Vt[((size_t)bh * 64 + d) * 2048 + j0 + c * 8] = o;
    }
}

// Flash attention, bf16 MFMA. Wave owns 16 query rows (wave-local softmax, DPP reductions).
// Q/K frags direct from global; Vt via LDS; P transposed through per-wave LDS (no barrier).
// Emits Oh/Ol split-bf16 [B,N,512] for the final split-GEMM.
__global__ __launch_bounds__(256) void attn_kernel(
    const bf16* __restrict__ Qg, const bf16* __restrict__ Kg, const bf16* __restrict__ Vt,
    const unsigned* __restrict__ pseq, const unsigned* __restrict__ psp,
    bf16* __restrict__ Oh, bf16* __restrict__ Ol) {
    __shared__ bf16 VT[64 * 72];       // [d][j], stride 72 -> uniform-8 b128 windows
    __shared__ bf16 P[4 * 16 * 72];    // per-wave [16 m][72 j]
    __shared__ unsigned Mw[64 * 2];    // combined mask words per query row

    int t = threadIdx.x;
    int wave = t >> 6, lane = t & 63, l = lane & 15, quad = lane >> 4;
    int bh = blockIdx.y, b = bh >> 3, h = bh & 7, par = h & 1;
    int i0 = blockIdx.x * 64;

    // Q frags in registers for the whole kernel (A[m=l][k], 2 k-chunks)
    const bf16* Qp = Qg + ((size_t)bh * 2048 + i0 + wave * 16 + l) * 64;
    bf16x8 qf0 = *(const bf16x8*)&Qp[quad * 8];
    bf16x8 qf1 = *(const bf16x8*)&Qp[32 + quad * 8];

    f32x4 o_acc[4] = {};
    float m_run[4], l_run[4];
#pragma unroll
    for (int r = 0; r < 4; ++r) { m_run[r] = -INFINITY; l_run[r] = 0.f; }

    const unsigned* seqrow = pseq + ((size_t)b * 2048 + i0) * 64;
    const unsigned* sprow = psp + ((size_t)par * 2048 + i0) * 64;
    bf16* Pw = P + wave * 16 * 72;

    for (int j0 = 0; j0 < 2048; j0 += 64) {
        // K frags direct from global (VMEM, overlaps the barrier)
        bf16x8 kf[4][2];
#pragma unroll
        for (int nc = 0; nc < 4; ++nc) {
            const bf16* Kp = Kg + ((size_t)bh * 2048 + j0 + nc * 16 + l) * 64 + quad * 8;
            kf[nc][0] = *(const bf16x8*)&Kp[0];
            kf[nc][1] = *(const bf16x8*)&Kp[32];
        }
        __syncthreads();  // prev tile's VT/Mw reads done
#pragma unroll
        for (int it = 0; it < 2; ++it) {
            int u = it * 256 + t;
            int d = u >> 3, c = u & 7;
            *(bf16x8*)&VT[d * 72 + c * 8] = *(const bf16x8*)&Vt[((size_t)bh * 64 + d) * 2048 + j0 + c * 8];
        }
        if (t < 128) {
            int r = t >> 1, wsel = t & 1;
            int w = (j0 >> 5) + wsel;
            Mw[r * 2 + wsel] = seqrow[r * 64 + w] & sprow[r * 64 + w];
        }
        __syncthreads();

        // S = Q K^T (fp32 accum)
        f32x4 s[4] = {};
#pragma unroll
        for (int nc = 0; nc < 4; ++nc) {
            s[nc] = MFMA(qf0, kf[nc][0], s[nc]);
            s[nc] = MFMA(qf1, kf[nc][1], s[nc]);
        }

        // mask (-1e9 replace, matching reference) + online softmax
        float p[4][4];
#pragma unroll
        for (int r = 0; r < 4; ++r) {
            int mrow = wave * 16 + quad * 4 + r;
            unsigned w0 = Mw[mrow * 2], w1 = Mw[mrow * 2 + 1];
            float sv0 = ((w0 >> l) & 1u) ? s[0][r] : NEGV;
            float sv1 = ((w0 >> (16 + l)) & 1u) ? s[1][r] : NEGV;
            float sv2 = ((w1 >> l) & 1u) ? s[2][r] : NEGV;
            float sv3 = ((w1 >> (16 + l)) & 1u) ? s[3][r] : NEGV;
            float mx = fmaxf(fmaxf(sv0, sv1), fmaxf(sv2, sv3));
            mx = red_max16(mx);
            float mnew = fmaxf(m_run[r], mx);
            float alpha = __expf(m_run[r] - mnew);
            m_run[r] = mnew;
            float e0 = __expf(sv0 - mnew);
            float e1 = __expf(sv1 - mnew);
            float e2 = __expf(sv2 - mnew);
            float e3 = __expf(sv3 - mnew);
            p[0][r] = e0; p[1][r] = e1; p[2][r] = e2; p[3][r] = e3;
            float ssum = red_sum16(e0 + e1 + e2 + e3);
            l_run[r] = l_run[r] * alpha + ssum;
            o_acc[0][r] *= alpha;
            o_acc[1][r] *= alpha;
            o_acc[2][r] *= alpha;
            o_acc[3][r] *= alpha;
        }

        // P -> per-wave LDS (transpose to A-operand layout); same-wave, no barrier needed
#pragma unroll
        for (int nc = 0; nc < 4; ++nc) {
#pragma unroll
            for (int r = 0; r < 4; ++r)
                Pw[(quad * 4 + r) * 72 + nc * 16 + l] = (bf16)p[nc][r];
        }

        // O += P V
#pragma unroll
        for (int kc = 0; kc < 2; ++kc) {
            bf16x8 a = *(const bf16x8*)&Pw[l * 72 + kc * 32 + quad * 8];
#pragma unroll
            for (int dc = 0; dc < 4; ++dc) {
                bf16x8 vb = *(const bf16x8*)&VT[(dc * 16 + l) * 72 + kc * 32 + quad * 8];
                o_acc[dc] = MFMA(a, vb, o_acc[dc]);
            }
        }
    }

    // epilogue: normalize, emit split-bf16 O
#pragma unroll
    for (int r = 0; r < 4; ++r) {
        float inv = 1.0f / l_run[r];
        int tok = i0 + wave * 16 + quad * 4 + r;
        size_t base = ((size_t)b * 2048 + tok) * 512 + h * 64 + l;
#pragma unroll
        for (int dc = 0; dc < 4; ++dc) {
            float val = o_acc[dc][r] * inv;
            bf16 hi = (bf16)val;
            Oh[base + dc * 16] = hi;
            Ol[base + dc * 16] = (bf16)(val - (float)hi);
        }
    }
}

extern "C" void kernel_launch(void* const* d_in, const int* in_sizes, int n_in,
                              void* d_out, int out_size, void* d_ws, size_t ws_size,
                              hipStream_t stream) {
    const float* x = (const float*)d_in[0];
    const float* Wq = (const float*)d_in[1];
    const float* Wk = (const float*)d_in[2];
    const float* Wv = (const float*)d_in[3];
    const float* Wo = (const float*)d_in[4];
    const int* seqm = (const int*)d_in[5];
    const int* spm = (const int*)d_in[6];
    float* out = (float*)d_out;

    const size_t E = 2097152;  // 2*2048*512 elements
    bf16* xb = (bf16*)d_ws;            // 4 MB
    bf16* Wb = xb + E;                 // 3x512x512
    bf16* Woh = Wb + 786432;
    bf16* Wol = Woh + 262144;
    bf16* Qg = Wol + 262144;           // [B,H,N,64] bf16
    bf16* Kg = Qg + E;
    bf16* Vg = Kg + E;
    bf16* Vtg = Vg + E;                // [bh][64][2048]
    bf16* Ohb = Vtg + E;               // [B,N,512] split hi
    bf16* Olb = Ohb + E;
    unsigned* pseq = (unsigned*)(Olb + E);  // [2][2048][64] words
    unsigned* psp = pseq + 262144;

    hipLaunchKernelGGL(pack_mask, dim3(1024), dim3(256), 0, stream, seqm, pseq);
    hipLaunchKernelGGL(pack_mask, dim3(1024), dim3(256), 0, stream, spm, psp);
    hipLaunchKernelGGL(cvt_bf16, dim3(1024), dim3(256), 0, stream, x, xb);
    hipLaunchKernelGGL(cvt_weights, dim3(128, 4), dim3(256), 0, stream, Wq, Wk, Wv, Wo, Wb, Woh, Wol);

    dim3 gg(64, 8);
    hipLaunchKernelGGL(gemm_qkv, gg, dim3(256), 0, stream, xb, Wb, Qg, 0.125f);
    hipLaunchKernelGGL(gemm_qkv, gg, dim3(256), 0, stream, xb, Wb + 262144, Kg, 1.0f);
    hipLaunchKernelGGL(gemm_qkv, gg, dim3(256), 0, stream, xb, Wb + 524288, Vg, 1.0f);
    hipLaunchKernelGGL(transpose_v, dim3(32, 16), dim3(256), 0, stream, Vg, Vtg);

    hipLaunchKernelGGL(attn_kernel, dim3(32, 16), dim3(256), 0, stream, Qg, Kg, Vtg, pseq, psp, Ohb, Olb);

    hipLaunchKernelGGL(gemm_out, gg, dim3(256), 0, stream, Ohb, Olb, Woh, Wol, out);
}